// Round 2
// baseline (335.498 us; speedup 1.0000x reference)
//
#include <hip/hip_runtime.h>
#include <hip/hip_bf16.h>

// Problem constants (B=4, S=2048, D=1024, E=8, F=4096)
#define TOKENS   8192
#define DDIM     1024
#define NEXP     8
#define FDIM     4096
#define CAPACITY 1280

typedef __attribute__((ext_vector_type(8))) __bf16 bf16x8;
typedef __attribute__((ext_vector_type(4))) __bf16 bf16x4;
typedef __attribute__((ext_vector_type(4))) float  f32x4;

typedef __attribute__((address_space(1))) const void gvoid_t;
typedef __attribute__((address_space(3))) void       lvoid_t;

__device__ __forceinline__ void async16(const void* g, void* l) {
  // 16B per lane, LDS dest = wave-uniform base + lane*16 (HW behavior)
  __builtin_amdgcn_global_load_lds((gvoid_t*)g, (lvoid_t*)l, 16, 0, 0);
}

// ---------------- gating: logits, softmax, top-1 (all f32, must match ref routing) --------
__global__ void gate_kernel(const float* __restrict__ x, const float* __restrict__ gw,
                            int* __restrict__ eidx, float* __restrict__ prob) {
  const int t = blockIdx.x;
  const int lane = threadIdx.x;           // 64 threads
  const float* xp = x + (size_t)t * DDIM;
  float acc[NEXP];
#pragma unroll
  for (int e = 0; e < NEXP; ++e) acc[e] = 0.f;
#pragma unroll 4
  for (int i = 0; i < DDIM / 64; ++i) {
    const int d = i * 64 + lane;
    const float xv = xp[d];
    const f32x4 g0 = *(const f32x4*)(gw + d * NEXP);
    const f32x4 g1 = *(const f32x4*)(gw + d * NEXP + 4);
    acc[0] += xv * g0[0]; acc[1] += xv * g0[1];
    acc[2] += xv * g0[2]; acc[3] += xv * g0[3];
    acc[4] += xv * g1[0]; acc[5] += xv * g1[1];
    acc[6] += xv * g1[2]; acc[7] += xv * g1[3];
  }
#pragma unroll
  for (int e = 0; e < NEXP; ++e) {
    float v = acc[e];
#pragma unroll
    for (int off = 32; off; off >>= 1) v += __shfl_xor(v, off);
    acc[e] = v;
  }
  if (lane == 0) {
    float m = acc[0]; int mi = 0;
#pragma unroll
    for (int e = 1; e < NEXP; ++e) if (acc[e] > m) { m = acc[e]; mi = e; }  // first-occurrence argmax
    float s = 0.f;
#pragma unroll
    for (int e = 0; e < NEXP; ++e) s += __expf(acc[e] - m);
    eidx[t] = mi;
    prob[t] = 1.f / s;       // softmax prob of the argmax expert
  }
}

// ---------------- deterministic per-expert cumsum positions + slot->token map -------------
__global__ void scan_kernel(const int* __restrict__ eidx, int* __restrict__ src) {
  __shared__ int buf[2][NEXP][256];
  const int tid = threadIdx.x;            // 256 threads, 1 block
  for (int i = tid; i < NEXP * CAPACITY; i += 256) src[i] = -1;
  const int t0 = tid * (TOKENS / 256);    // 32 tokens per thread
#pragma unroll
  for (int e = 0; e < NEXP; ++e) buf[0][e][tid] = 0;
  for (int k = 0; k < TOKENS / 256; ++k) {
    const int e = eidx[t0 + k];
    buf[0][e][tid]++;                     // LDS histogram (avoids scratch spill)
  }
  __syncthreads();
  int cur = 0;
  for (int off = 1; off < 256; off <<= 1) {   // Hillis-Steele inclusive scan over threads
#pragma unroll
    for (int e = 0; e < NEXP; ++e) {
      int v = buf[cur][e][tid];
      if (tid >= off) v += buf[cur][e][tid - off];
      buf[cur ^ 1][e][tid] = v;
    }
    __syncthreads();
    cur ^= 1;
  }
  // exclusive base -> running counters in the other buffer (own slot only, no race)
#pragma unroll
  for (int e = 0; e < NEXP; ++e)
    buf[cur ^ 1][e][tid] = (tid > 0) ? buf[cur][e][tid - 1] : 0;
  for (int k = 0; k < TOKENS / 256; ++k) {
    const int t = t0 + k;
    const int e = eidx[t];
    const int p = buf[cur ^ 1][e][tid]++;
    if (p < CAPACITY) src[e * CAPACITY + p] = t;   // p>=CAP => token dropped
  }
}

// ---------------- dispatch: scatter tokens (f32 -> bf16) into [E*CAP, D]; zero empty slots
__global__ void dispatch_kernel(const float* __restrict__ tokens, const int* __restrict__ src,
                                __bf16* __restrict__ Xb) {
  const int slot = blockIdx.x;            // E*CAP blocks
  const int tid  = threadIdx.x;           // 256 threads, 4 elems each
  const int t = src[slot];
  bf16x4* dst = (bf16x4*)(Xb + (size_t)slot * DDIM);
  bf16x4 o;
  if (t >= 0) {
    const f32x4 v = ((const f32x4*)(tokens + (size_t)t * DDIM))[tid];
    o[0] = (__bf16)v[0]; o[1] = (__bf16)v[1]; o[2] = (__bf16)v[2]; o[3] = (__bf16)v[3];
  } else {
    o[0] = (__bf16)0.f; o[1] = (__bf16)0.f; o[2] = (__bf16)0.f; o[3] = (__bf16)0.f;
  }
  dst[tid] = o;
}

// ---------------- weight convert f32->bf16 with transpose: w[e][R][C] -> wt[e][C][R] ------
__global__ void transpose_convert_kernel(const float* __restrict__ w, __bf16* __restrict__ wt,
                                         int R, int C) {
  __shared__ __bf16 tile[64][65];         // +1 pad: conflict-free transpose
  const int e = blockIdx.z;
  const float* wp = w + (size_t)e * R * C;
  __bf16* op = wt + (size_t)e * R * C;
  const int c0 = blockIdx.x * 64, r0 = blockIdx.y * 64;
  const int tx = threadIdx.x, ty = threadIdx.y;   // (64,4)
#pragma unroll
  for (int i = 0; i < 16; ++i) {
    const int r = ty + i * 4;
    tile[r][tx] = (__bf16)wp[(size_t)(r0 + r) * C + c0 + tx];
  }
  __syncthreads();
#pragma unroll
  for (int i = 0; i < 16; ++i) {
    const int cc = ty + i * 4;
    op[(size_t)(c0 + cc) * R + r0 + tx] = tile[tx][cc];
  }
}

// ---------------- grouped GEMM: C[e] = A[e][M,K] @ B[e][N,K]^T  (both K-contiguous) -------
// MODE 0: relu -> bf16 into Cbf.   MODE 1: scatter f32 out[t] = prob[t]*val via src.
template <int MODE>
__global__ __launch_bounds__(256, 2)
void gemm_kernel(const __bf16* __restrict__ A, const __bf16* __restrict__ B,
                 __bf16* __restrict__ Cbf, float* __restrict__ out,
                 const int* __restrict__ src, const float* __restrict__ prob,
                 int N, int K, size_t sA, size_t sB, size_t sC) {
  __shared__ __bf16 lds[2][128 * 64];     // [0]=A tile [128][64], [1]=B tile [128][64]
  const int e  = blockIdx.z;
  const int n0 = blockIdx.x * 128;
  const int m0 = blockIdx.y * 128;
  const __bf16* Ae = A + (size_t)e * sA;
  const __bf16* Be = B + (size_t)e * sB;
  const int tid = threadIdx.x;
  const int wave = tid >> 6, lane = tid & 63;
  const int wr = wave >> 1, wc = wave & 1;  // wave -> 64x64 quadrant
  const int rl = lane & 15, gl = lane >> 4;
  const f32x4 zero = {0.f, 0.f, 0.f, 0.f};
  f32x4 acc[4][4];
#pragma unroll
  for (int m = 0; m < 4; ++m)
#pragma unroll
    for (int n = 0; n < 4; ++n) acc[m][n] = zero;

  for (int kt = 0; kt < K; kt += 64) {
    // stage 16KB A + 16KB B via global_load_lds; LDS linear, source pre-swizzled
    // (XOR granule with row&7 so swizzled ds_read is conflict-free — G4/m173 pattern)
#pragma unroll
    for (int i = 0; i < 4; ++i) {
      const int s   = (wave * 4 + i) * 64 + lane;   // 16B slot id
      const int row = s >> 3;                       // tile row (8 granules/row)
      const int cg  = (s & 7) ^ (row & 7);          // swizzled source granule
      async16(Ae + (size_t)(m0 + row) * K + kt + cg * 8, &lds[0][(wave * 4 + i) * 512]);
      async16(Be + (size_t)(n0 + row) * K + kt + cg * 8, &lds[1][(wave * 4 + i) * 512]);
    }
    __syncthreads();                                // drains vmcnt before barrier
    const char* la = (const char*)&lds[0][0];
    const char* lb = (const char*)&lds[1][0];
#pragma unroll
    for (int kk = 0; kk < 2; ++kk) {
      bf16x8 af[4], bfv[4];
#pragma unroll
      for (int m = 0; m < 4; ++m) {
        const int row = wr * 64 + m * 16 + rl;
        const int g = (kk * 4 + gl) ^ (row & 7);
        af[m] = *(const bf16x8*)(la + row * 128 + g * 16);
      }
#pragma unroll
      for (int n = 0; n < 4; ++n) {
        const int row = wc * 64 + n * 16 + rl;
        const int g = (kk * 4 + gl) ^ (row & 7);
        bfv[n] = *(const bf16x8*)(lb + row * 128 + g * 16);
      }
#pragma unroll
      for (int m = 0; m < 4; ++m)
#pragma unroll
        for (int n = 0; n < 4; ++n)
          acc[m][n] = __builtin_amdgcn_mfma_f32_16x16x32_bf16(af[m], bfv[n], acc[m][n], 0, 0, 0);
    }
    __syncthreads();
  }

  // C/D layout: col = lane&15, row = (lane>>4)*4 + reg  [m89/m91 verified]
  if (MODE == 0) {
    __bf16* Ce = Cbf + (size_t)e * sC;
#pragma unroll
    for (int m = 0; m < 4; ++m)
#pragma unroll
      for (int j = 0; j < 4; ++j) {
        const int row = m0 + wr * 64 + m * 16 + gl * 4 + j;
#pragma unroll
        for (int n = 0; n < 4; ++n) {
          const int col = n0 + wc * 64 + n * 16 + rl;
          float v = acc[m][n][j];
          v = v > 0.f ? v : 0.f;                    // fused ReLU
          Ce[(size_t)row * N + col] = (__bf16)v;
        }
      }
  } else {
#pragma unroll
    for (int m = 0; m < 4; ++m)
#pragma unroll
      for (int j = 0; j < 4; ++j) {
        const int slot = m0 + wr * 64 + m * 16 + gl * 4 + j;
        const int t = src[e * CAPACITY + slot];
        if (t >= 0) {
          const float p = prob[t];
          float* op = out + (size_t)t * N;
#pragma unroll
          for (int n = 0; n < 4; ++n) {
            const int col = n0 + wc * 64 + n * 16 + rl;
            op[col] = p * acc[m][n][j];             // fused combine (scale + scatter)
          }
        }
      }
  }
}

extern "C" void kernel_launch(void* const* d_in, const int* in_sizes, int n_in,
                              void* d_out, int out_size, void* d_ws, size_t ws_size,
                              hipStream_t stream) {
  const float* x  = (const float*)d_in[0];
  const float* gw = (const float*)d_in[1];
  const float* w1 = (const float*)d_in[2];
  const float* w2 = (const float*)d_in[3];
  float* out = (float*)d_out;

  char* ws = (char*)d_ws;
  size_t off = 0;
  auto alloc = [&](size_t bytes) {
    void* p = ws + off;
    off += (bytes + 255) & ~(size_t)255;
    return p;
  };
  __bf16* W1bT = (__bf16*)alloc((size_t)NEXP * FDIM * DDIM * 2);   // [E][F][D] bf16
  __bf16* W2bT = (__bf16*)alloc((size_t)NEXP * DDIM * FDIM * 2);   // [E][D][F] bf16
  __bf16* Xb   = (__bf16*)alloc((size_t)NEXP * CAPACITY * DDIM * 2);
  __bf16* Hb   = (__bf16*)alloc((size_t)NEXP * CAPACITY * FDIM * 2);
  int*   eidx  = (int*)alloc(TOKENS * sizeof(int));
  float* prob  = (float*)alloc(TOKENS * sizeof(float));
  int*   srcm  = (int*)alloc(NEXP * CAPACITY * sizeof(int));
  (void)ws_size; (void)in_sizes; (void)n_in;

  hipMemsetAsync(d_out, 0, (size_t)out_size * sizeof(float), stream);  // dropped tokens -> 0

  gate_kernel<<<TOKENS, 64, 0, stream>>>(x, gw, eidx, prob);
  scan_kernel<<<1, 256, 0, stream>>>(eidx, srcm);
  dispatch_kernel<<<NEXP * CAPACITY, 256, 0, stream>>>(x, srcm, Xb);
  transpose_convert_kernel<<<dim3(FDIM / 64, DDIM / 64, NEXP), dim3(64, 4), 0, stream>>>(
      w1, W1bT, DDIM, FDIM);
  transpose_convert_kernel<<<dim3(DDIM / 64, FDIM / 64, NEXP), dim3(64, 4), 0, stream>>>(
      w2, W2bT, FDIM, DDIM);
  // H = relu(Xb @ W1^T)
  gemm_kernel<0><<<dim3(FDIM / 128, CAPACITY / 128, NEXP), 256, 0, stream>>>(
      Xb, W1bT, Hb, nullptr, nullptr, nullptr,
      FDIM, DDIM, (size_t)CAPACITY * DDIM, (size_t)FDIM * DDIM, (size_t)CAPACITY * FDIM);
  // out[t] = prob[t] * (H @ W2^T)[slot]
  gemm_kernel<1><<<dim3(DDIM / 128, CAPACITY / 128, NEXP), 256, 0, stream>>>(
      Hb, W2bT, nullptr, out, srcm, prob,
      DDIM, FDIM, (size_t)CAPACITY * FDIM, (size_t)DDIM * FDIM, 0);
}